// Round 2
// baseline (165.879 us; speedup 1.0000x reference)
//
#include <hip/hip_runtime.h>
#include <hip/hip_bf16.h>
#include <stdint.h>

#define B_ 4096
#define L_ 80
#define V_ 256
#define H_ 512

typedef __attribute__((ext_vector_type(4))) float f32x4;
typedef __attribute__((ext_vector_type(8))) short bf16x8;

// round-to-nearest-even f32 -> bf16 bits (matches __float2bfloat16 for
// normal inputs; inputs here are small normals)
static __device__ __forceinline__ unsigned short f2bf(float x) {
  union { float f; unsigned int u; } a;
  a.f = x;
  unsigned int r = a.u + 0x7fffu + ((a.u >> 16) & 1u);
  return (unsigned short)(r >> 16);
}

// ---------------------------------------------------------------------------
// Kernel 0: W2 [k=512][n=512] f32 -> W2T [n=512][k=512] bf16, LDS-tiled.
// ---------------------------------------------------------------------------
__global__ __launch_bounds__(256) void w2_transpose(
    const float* __restrict__ W2, unsigned short* __restrict__ W2T) {
  __shared__ float tile[32][33];
  const int ti = blockIdx.x;  // k-tile
  const int tj = blockIdx.y;  // n-tile
  const int r = threadIdx.x >> 5;   // 0..7
  const int c = threadIdx.x & 31;   // 0..31
#pragma unroll
  for (int rr = r; rr < 32; rr += 8)
    tile[rr][c] = W2[(size_t)(ti * 32 + rr) * H_ + tj * 32 + c];
  __syncthreads();
#pragma unroll
  for (int rr = r; rr < 32; rr += 8)
    W2T[(size_t)(tj * 32 + rr) * H_ + ti * 32 + c] = f2bf(tile[c][rr]);
}

// ---------------------------------------------------------------------------
// Kernel 1: gather-sum over 80 positions + b1 + relu -> h (bf16) [B][H]
// 8 batch rows / block, 512 threads = 4 groups x 128 lanes; each lane owns
// 4 channels (float4). Row offset is wave-uniform -> readfirstlane to SGPR.
// ---------------------------------------------------------------------------
__global__ __launch_bounds__(512) void encode_gather(
    const int* __restrict__ msg, const float* __restrict__ W1,
    const float* __restrict__ b1, unsigned short* __restrict__ h) {
  const int BT = 8;
  __shared__ int offs[BT * L_];  // element offsets into W1
  const int t = threadIdx.x;
  const int b0 = blockIdx.x * BT;
  const int g = t >> 7;          // row group 0..3
  const int c4 = (t & 127) * 4;  // channel base

  for (int i = t; i < BT * L_; i += 512) {
    int b = i / L_, l = i - b * L_;
    offs[i] = (l * V_ + msg[(b0 + b) * L_ + l]) * H_;
  }
  __syncthreads();

  const int br0 = g * 2, br1 = g * 2 + 1;
  f32x4 acc0 = {}, acc1 = {};

#pragma unroll 4
  for (int l = 0; l < L_; ++l) {
    int o0 = __builtin_amdgcn_readfirstlane(offs[br0 * L_ + l]);
    int o1 = __builtin_amdgcn_readfirstlane(offs[br1 * L_ + l]);
    acc0 += *reinterpret_cast<const f32x4*>(W1 + o0 + c4);
    acc1 += *reinterpret_cast<const f32x4*>(W1 + o1 + c4);
  }

  const f32x4 bias = *reinterpret_cast<const f32x4*>(b1 + c4);
  f32x4 v0 = acc0 + bias, v1 = acc1 + bias;
  ushort4 o0, o1;
  o0.x = f2bf(v0[0] > 0.f ? v0[0] : 0.f);
  o0.y = f2bf(v0[1] > 0.f ? v0[1] : 0.f);
  o0.z = f2bf(v0[2] > 0.f ? v0[2] : 0.f);
  o0.w = f2bf(v0[3] > 0.f ? v0[3] : 0.f);
  o1.x = f2bf(v1[0] > 0.f ? v1[0] : 0.f);
  o1.y = f2bf(v1[1] > 0.f ? v1[1] : 0.f);
  o1.z = f2bf(v1[2] > 0.f ? v1[2] : 0.f);
  o1.w = f2bf(v1[3] > 0.f ? v1[3] : 0.f);
  *reinterpret_cast<ushort4*>(&h[(size_t)(b0 + br0) * H_ + c4]) = o0;
  *reinterpret_cast<ushort4*>(&h[(size_t)(b0 + br1) * H_ + c4]) = o1;
}

// ---------------------------------------------------------------------------
// Kernel 2: out = relu(h @ W2 + b2), bf16 MFMA 16x16x32, fp32 accum/output.
// Block tile 128x64, 4 waves 2x2 -> wave tile 64x32 (4x2 fragments).
// C/D mapping: col = lane&15, row = (lane>>4)*4 + reg (m89-verified).
// ---------------------------------------------------------------------------
__global__ __launch_bounds__(256) void gemm_out(
    const unsigned short* __restrict__ h, const unsigned short* __restrict__ W2T,
    const float* __restrict__ b2, float* __restrict__ out) {
  const int wid = threadIdx.x >> 6;   // 0..3
  const int lane = threadIdx.x & 63;
  const int wm = wid >> 1, wn = wid & 1;
  const int bm = blockIdx.x * 128;
  const int bn = blockIdx.y * 64;
  const int lr = lane & 15;
  const int lq = lane >> 4;  // 0..3

  f32x4 acc[4][2] = {};

  const unsigned short* aptr = h + (size_t)(bm + wm * 64 + lr) * H_ + lq * 8;
  const unsigned short* bptr = W2T + (size_t)(bn + wn * 32 + lr) * H_ + lq * 8;

  for (int kt = 0; kt < H_ / 32; ++kt) {
    const int ko = kt * 32;
    bf16x8 a[4], bb[2];
#pragma unroll
    for (int mi = 0; mi < 4; ++mi)
      a[mi] = *reinterpret_cast<const bf16x8*>(aptr + (size_t)mi * 16 * H_ + ko);
#pragma unroll
    for (int ni = 0; ni < 2; ++ni)
      bb[ni] = *reinterpret_cast<const bf16x8*>(bptr + (size_t)ni * 16 * H_ + ko);
#pragma unroll
    for (int mi = 0; mi < 4; ++mi)
#pragma unroll
      for (int ni = 0; ni < 2; ++ni)
        acc[mi][ni] = __builtin_amdgcn_mfma_f32_16x16x32_bf16(
            a[mi], bb[ni], acc[mi][ni], 0, 0, 0);
  }

#pragma unroll
  for (int mi = 0; mi < 4; ++mi) {
#pragma unroll
    for (int ni = 0; ni < 2; ++ni) {
      const int n = bn + wn * 32 + ni * 16 + lr;
      const float bias = b2[n];
#pragma unroll
      for (int r = 0; r < 4; ++r) {
        const int m = bm + wm * 64 + mi * 16 + lq * 4 + r;
        float v = acc[mi][ni][r] + bias;
        out[(size_t)m * H_ + n] = v > 0.f ? v : 0.f;
      }
    }
  }
}

// ---------------------------------------------------------------------------
extern "C" void kernel_launch(void* const* d_in, const int* in_sizes, int n_in,
                              void* d_out, int out_size, void* d_ws, size_t ws_size,
                              hipStream_t stream) {
  const int* msg   = (const int*)d_in[0];
  const float* W1  = (const float*)d_in[1];
  const float* b1  = (const float*)d_in[2];
  const float* W2  = (const float*)d_in[3];
  const float* b2  = (const float*)d_in[4];
  float* out = (float*)d_out;

  unsigned short* W2T = (unsigned short*)d_ws;                        // 512 KB
  unsigned short* h   = (unsigned short*)((char*)d_ws + H_ * H_ * 2); // 4 MB

  hipLaunchKernelGGL(w2_transpose, dim3(H_ / 32, H_ / 32), dim3(256), 0, stream,
                     W2, W2T);
  hipLaunchKernelGGL(encode_gather, dim3(B_ / 8), dim3(512), 0, stream,
                     msg, W1, b1, h);
  hipLaunchKernelGGL(gemm_out, dim3(B_ / 128, H_ / 64), dim3(256), 0, stream,
                     h, W2T, b2, out);
}

// Round 3
// 140.751 us; speedup vs baseline: 1.1785x; 1.1785x over previous
//
#include <hip/hip_runtime.h>
#include <hip/hip_bf16.h>
#include <stdint.h>

#define B_ 4096
#define L_ 80
#define V_ 256
#define H_ 512

typedef __attribute__((ext_vector_type(4))) float f32x4;
typedef __attribute__((ext_vector_type(8))) short bf16x8;
typedef __attribute__((ext_vector_type(8))) unsigned short ushort8;

static __device__ __forceinline__ unsigned short f2bf(float x) {
  union { float f; unsigned int u; } a;
  a.f = x;
  unsigned int r = a.u + 0x7fffu + ((a.u >> 16) & 1u);
  return (unsigned short)(r >> 16);
}
static __device__ __forceinline__ float bf2f(unsigned short u) {
  union { unsigned int i; float f; } a;
  a.i = ((unsigned int)u) << 16;
  return a.f;
}

// ---------------------------------------------------------------------------
// Kernel 0 (prep): blocks [0,256): W2 -> W2T bf16 (LDS-tiled transpose);
//                  blocks [256,..): W1 f32 -> W1b bf16, 8 elems/thread.
// ---------------------------------------------------------------------------
__global__ __launch_bounds__(256) void prep(
    const float* __restrict__ W2, const float* __restrict__ W1,
    unsigned short* __restrict__ W2T, unsigned short* __restrict__ W1b) {
  const int bid = blockIdx.x;
  if (bid < 256) {
    __shared__ float tile[32][33];
    const int ti = bid & 15, tj = bid >> 4;
    const int r = threadIdx.x >> 5, c = threadIdx.x & 31;
#pragma unroll
    for (int rr = r; rr < 32; rr += 8)
      tile[rr][c] = W2[(size_t)(ti * 32 + rr) * H_ + tj * 32 + c];
    __syncthreads();
#pragma unroll
    for (int rr = r; rr < 32; rr += 8)
      W2T[(size_t)(tj * 32 + rr) * H_ + ti * 32 + c] = f2bf(tile[c][rr]);
  } else {
    const size_t i8 = ((size_t)(bid - 256) * 256 + threadIdx.x) * 8;
    f32x4 v0 = *reinterpret_cast<const f32x4*>(W1 + i8);
    f32x4 v1 = *reinterpret_cast<const f32x4*>(W1 + i8 + 4);
    ushort8 o;
    o[0] = f2bf(v0[0]); o[1] = f2bf(v0[1]); o[2] = f2bf(v0[2]); o[3] = f2bf(v0[3]);
    o[4] = f2bf(v1[0]); o[5] = f2bf(v1[1]); o[6] = f2bf(v1[2]); o[7] = f2bf(v1[3]);
    *reinterpret_cast<ushort8*>(W1b + i8) = o;
  }
}

// ---------------------------------------------------------------------------
// Kernel 1: gather-sum (bf16 W1) + b1 + relu -> h (bf16) [B][H]
// BT=16 rows/block (best measured L2 reuse), 512 thr = 8 waves; each wave
// owns 2 rows; each lane owns 8 channels (16 B loads). fp32 accumulate.
// ---------------------------------------------------------------------------
__global__ __launch_bounds__(512) void encode_gather_bf(
    const int* __restrict__ msg, const unsigned short* __restrict__ W1b,
    const float* __restrict__ b1, unsigned short* __restrict__ h) {
  const int BT = 16;
  __shared__ int offs[BT * L_];
  const int t = threadIdx.x;
  const int b0 = blockIdx.x * BT;
  const int w = t >> 6;
  const int lane = t & 63;
  const int c8 = lane * 8;

  for (int i = t; i < BT * L_; i += 512) {
    int b = i / L_, l = i - b * L_;
    offs[i] = (l * V_ + msg[(b0 + b) * L_ + l]) * H_;
  }
  __syncthreads();

  const int r0 = w * 2, r1 = r0 + 1;
  float a0[8] = {}, a1[8] = {};

#pragma unroll 4
  for (int l = 0; l < L_; ++l) {
    int o0 = __builtin_amdgcn_readfirstlane(offs[r0 * L_ + l]);
    int o1 = __builtin_amdgcn_readfirstlane(offs[r1 * L_ + l]);
    ushort8 v0 = *reinterpret_cast<const ushort8*>(W1b + o0 + c8);
    ushort8 v1 = *reinterpret_cast<const ushort8*>(W1b + o1 + c8);
#pragma unroll
    for (int j = 0; j < 8; ++j) {
      a0[j] += bf2f(v0[j]);
      a1[j] += bf2f(v1[j]);
    }
  }

  ushort8 o0, o1;
#pragma unroll
  for (int j = 0; j < 8; ++j) {
    float bias = b1[c8 + j];
    float x0 = a0[j] + bias, x1 = a1[j] + bias;
    o0[j] = f2bf(x0 > 0.f ? x0 : 0.f);
    o1[j] = f2bf(x1 > 0.f ? x1 : 0.f);
  }
  *reinterpret_cast<ushort8*>(&h[(size_t)(b0 + r0) * H_ + c8]) = o0;
  *reinterpret_cast<ushort8*>(&h[(size_t)(b0 + r1) * H_ + c8]) = o1;
}

// ---------------------------------------------------------------------------
// Kernel 1b (fallback if ws too small for W1b): f32 W1 gather, BT=16.
// ---------------------------------------------------------------------------
__global__ __launch_bounds__(512) void encode_gather_f32(
    const int* __restrict__ msg, const float* __restrict__ W1,
    const float* __restrict__ b1, unsigned short* __restrict__ h) {
  const int BT = 16;
  __shared__ int offs[BT * L_];
  const int t = threadIdx.x;
  const int b0 = blockIdx.x * BT;
  const int g = t >> 7;
  const int c4 = (t & 127) * 4;

  for (int i = t; i < BT * L_; i += 512) {
    int b = i / L_, l = i - b * L_;
    offs[i] = (l * V_ + msg[(b0 + b) * L_ + l]) * H_;
  }
  __syncthreads();

  f32x4 acc[4] = {};
#pragma unroll 2
  for (int l = 0; l < L_; ++l) {
#pragma unroll
    for (int rr = 0; rr < 4; ++rr) {
      int o = __builtin_amdgcn_readfirstlane(offs[(g * 4 + rr) * L_ + l]);
      acc[rr] += *reinterpret_cast<const f32x4*>(W1 + o + c4);
    }
  }
  const f32x4 bias = *reinterpret_cast<const f32x4*>(b1 + c4);
#pragma unroll
  for (int rr = 0; rr < 4; ++rr) {
    f32x4 v = acc[rr] + bias;
    ushort4 o;
    o.x = f2bf(v[0] > 0.f ? v[0] : 0.f);
    o.y = f2bf(v[1] > 0.f ? v[1] : 0.f);
    o.z = f2bf(v[2] > 0.f ? v[2] : 0.f);
    o.w = f2bf(v[3] > 0.f ? v[3] : 0.f);
    *reinterpret_cast<ushort4*>(&h[(size_t)(b0 + g * 4 + rr) * H_ + c4]) = o;
  }
}

// ---------------------------------------------------------------------------
// Kernel 2: out = relu(h @ W2 + b2), bf16 MFMA 16x16x32, fp32 accum/output.
// 64x64 block tile, 4 waves 2x2 -> wave 32x32 (2x2 frags). 512 blocks.
// C/D mapping: col = lane&15, row = (lane>>4)*4 + reg (m89-verified).
// ---------------------------------------------------------------------------
__global__ __launch_bounds__(256) void gemm_out(
    const unsigned short* __restrict__ h, const unsigned short* __restrict__ W2T,
    const float* __restrict__ b2, float* __restrict__ out) {
  const int wid = threadIdx.x >> 6;
  const int lane = threadIdx.x & 63;
  const int wm = wid >> 1, wn = wid & 1;
  const int bm = blockIdx.x * 64;
  const int bn = blockIdx.y * 64;
  const int lr = lane & 15;
  const int lq = lane >> 4;

  f32x4 acc[2][2] = {};

  const unsigned short* aptr = h + (size_t)(bm + wm * 32 + lr) * H_ + lq * 8;
  const unsigned short* bptr = W2T + (size_t)(bn + wn * 32 + lr) * H_ + lq * 8;

#pragma unroll 2
  for (int kt = 0; kt < H_ / 32; ++kt) {
    const int ko = kt * 32;
    bf16x8 a[2], bb[2];
#pragma unroll
    for (int mi = 0; mi < 2; ++mi)
      a[mi] = *reinterpret_cast<const bf16x8*>(aptr + (size_t)mi * 16 * H_ + ko);
#pragma unroll
    for (int ni = 0; ni < 2; ++ni)
      bb[ni] = *reinterpret_cast<const bf16x8*>(bptr + (size_t)ni * 16 * H_ + ko);
#pragma unroll
    for (int mi = 0; mi < 2; ++mi)
#pragma unroll
      for (int ni = 0; ni < 2; ++ni)
        acc[mi][ni] = __builtin_amdgcn_mfma_f32_16x16x32_bf16(
            a[mi], bb[ni], acc[mi][ni], 0, 0, 0);
  }

#pragma unroll
  for (int mi = 0; mi < 2; ++mi) {
#pragma unroll
    for (int ni = 0; ni < 2; ++ni) {
      const int n = bn + wn * 32 + ni * 16 + lr;
      const float bias = b2[n];
#pragma unroll
      for (int r = 0; r < 4; ++r) {
        const int m = bm + wm * 32 + mi * 16 + lq * 4 + r;
        float v = acc[mi][ni][r] + bias;
        out[(size_t)m * H_ + n] = v > 0.f ? v : 0.f;
      }
    }
  }
}

// ---------------------------------------------------------------------------
extern "C" void kernel_launch(void* const* d_in, const int* in_sizes, int n_in,
                              void* d_out, int out_size, void* d_ws, size_t ws_size,
                              hipStream_t stream) {
  const int* msg   = (const int*)d_in[0];
  const float* W1  = (const float*)d_in[1];
  const float* b1  = (const float*)d_in[2];
  const float* W2  = (const float*)d_in[3];
  const float* b2  = (const float*)d_in[4];
  float* out = (float*)d_out;

  const size_t W2T_OFF = 0;
  const size_t H_OFF   = (size_t)H_ * H_ * 2;             // 512 KB
  const size_t W1B_OFF = H_OFF + (size_t)B_ * H_ * 2;     // +4 MB
  const size_t NEED    = W1B_OFF + (size_t)L_ * V_ * H_ * 2;  // +21 MB

  unsigned short* W2T = (unsigned short*)((char*)d_ws + W2T_OFF);
  unsigned short* h   = (unsigned short*)((char*)d_ws + H_OFF);
  unsigned short* W1b = (unsigned short*)((char*)d_ws + W1B_OFF);

  if (ws_size >= NEED) {
    // prep: 256 transpose blocks + W1-convert blocks (8 elems/thread)
    const int conv_blocks = (L_ * V_ * H_) / (256 * 8);  // 5120
    hipLaunchKernelGGL(prep, dim3(256 + conv_blocks), dim3(256), 0, stream,
                       W2, W1, W2T, W1b);
    hipLaunchKernelGGL(encode_gather_bf, dim3(B_ / 16), dim3(512), 0, stream,
                       msg, W1b, b1, h);
  } else {
    const int conv_blocks = 0;
    hipLaunchKernelGGL(prep, dim3(256 + conv_blocks), dim3(256), 0, stream,
                       W2, W1, W2T, W1b);
    hipLaunchKernelGGL(encode_gather_f32, dim3(B_ / 16), dim3(512), 0, stream,
                       msg, W1, b1, h);
  }

  hipLaunchKernelGGL(gemm_out, dim3(B_ / 64, H_ / 64), dim3(256), 0, stream,
                     h, W2T, b2, out);
}

// Round 4
// 128.658 us; speedup vs baseline: 1.2893x; 1.0940x over previous
//
#include <hip/hip_runtime.h>
#include <hip/hip_bf16.h>
#include <stdint.h>

#define B_ 4096
#define L_ 80
#define V_ 256
#define H_ 512
#define BT 16
#define HP 520  // padded LDS row stride (elems): bank-uniform, 16B-aligned

typedef __attribute__((ext_vector_type(4))) float f32x4;
typedef __attribute__((ext_vector_type(8))) short bf16x8;
typedef __attribute__((ext_vector_type(8))) unsigned short ushort8;

static __device__ __forceinline__ unsigned short f2bf(float x) {
  union { float f; unsigned int u; } a;
  a.f = x;
  unsigned int r = a.u + 0x7fffu + ((a.u >> 16) & 1u);
  return (unsigned short)(r >> 16);
}
static __device__ __forceinline__ float bf2f(unsigned short u) {
  union { unsigned int i; float f; } a;
  a.i = ((unsigned int)u) << 16;
  return a.f;
}

// ---------------------------------------------------------------------------
// Kernel 0 (prep): blocks [0, 5120): W1 f32 -> W1b bf16 (8 elems/thread);
//                  blocks [5120, 5376): W2 -> W2T bf16 (LDS-tiled transpose).
// ---------------------------------------------------------------------------
__global__ __launch_bounds__(256) void prep(
    const float* __restrict__ W2, const float* __restrict__ W1,
    unsigned short* __restrict__ W2T, unsigned short* __restrict__ W1b) {
  const int bid = blockIdx.x;
  if (bid < 5120) {
    const size_t i8 = ((size_t)bid * 256 + threadIdx.x) * 8;
    f32x4 v0 = *reinterpret_cast<const f32x4*>(W1 + i8);
    f32x4 v1 = *reinterpret_cast<const f32x4*>(W1 + i8 + 4);
    ushort8 o;
    o[0] = f2bf(v0[0]); o[1] = f2bf(v0[1]); o[2] = f2bf(v0[2]); o[3] = f2bf(v0[3]);
    o[4] = f2bf(v1[0]); o[5] = f2bf(v1[1]); o[6] = f2bf(v1[2]); o[7] = f2bf(v1[3]);
    *reinterpret_cast<ushort8*>(W1b + i8) = o;
  } else {
    __shared__ float tile[32][33];
    const int tb = bid - 5120;
    const int ti = tb & 15, tj = tb >> 4;
    const int r = threadIdx.x >> 5, c = threadIdx.x & 31;
#pragma unroll
    for (int rr = r; rr < 32; rr += 8)
      tile[rr][c] = W2[(size_t)(ti * 32 + rr) * H_ + tj * 32 + c];
    __syncthreads();
#pragma unroll
    for (int rr = r; rr < 32; rr += 8)
      W2T[(size_t)(tj * 32 + rr) * H_ + ti * 32 + c] = f2bf(tile[c][rr]);
  }
}

// ---------------------------------------------------------------------------
// Kernel 1 (fused): gather-sum(bf16 W1) + b1 + relu -> h-slab in LDS, then
// 16x512 @ 512x512 bf16 MFMA GEMM + b2 + relu -> out.
// 256 blocks x 512 threads (8 waves). Gather: wave w owns rows 2w,2w+1,
// lane owns 8 channels. GEMM: wave w owns output cols [w*64, w*64+64).
// LDS h-slab stride HP=520: ds_write/ds_read bank groups are uniform
// (8 lanes per 4-bank group = wave64 minimum).
// C/D mapping: col=lane&15, row=(lane>>4)*4+reg (m89-verified, R1-R3 passed).
// ---------------------------------------------------------------------------
__global__ __launch_bounds__(512) void fused_gather_gemm(
    const int* __restrict__ msg, const unsigned short* __restrict__ W1b,
    const float* __restrict__ b1, const unsigned short* __restrict__ W2T,
    const float* __restrict__ b2, float* __restrict__ out) {
  __shared__ int offs[BT * L_];
  __shared__ unsigned short hl[BT * HP];

  const int t = threadIdx.x;
  const int w = t >> 6;
  const int lane = t & 63;
  const int b0 = blockIdx.x * BT;

  for (int i = t; i < BT * L_; i += 512) {
    int b = i / L_, l = i - b * L_;
    offs[i] = (l * V_ + msg[(b0 + b) * L_ + l]) * H_;
  }
  __syncthreads();

  // ---- gather phase ----
  const int r0 = 2 * w, r1 = r0 + 1;
  const int c8 = lane * 8;
  float a0[8] = {}, a1[8] = {};

#pragma unroll 4
  for (int l = 0; l < L_; ++l) {
    int o0 = __builtin_amdgcn_readfirstlane(offs[r0 * L_ + l]);
    int o1 = __builtin_amdgcn_readfirstlane(offs[r1 * L_ + l]);
    ushort8 v0 = *reinterpret_cast<const ushort8*>(W1b + o0 + c8);
    ushort8 v1 = *reinterpret_cast<const ushort8*>(W1b + o1 + c8);
#pragma unroll
    for (int j = 0; j < 8; ++j) {
      a0[j] += bf2f(v0[j]);
      a1[j] += bf2f(v1[j]);
    }
  }

  ushort8 h0, h1;
#pragma unroll
  for (int j = 0; j < 8; ++j) {
    float bias = b1[c8 + j];
    float x0 = a0[j] + bias, x1 = a1[j] + bias;
    h0[j] = f2bf(x0 > 0.f ? x0 : 0.f);
    h1[j] = f2bf(x1 > 0.f ? x1 : 0.f);
  }
  *reinterpret_cast<ushort8*>(&hl[r0 * HP + c8]) = h0;
  *reinterpret_cast<ushort8*>(&hl[r1 * HP + c8]) = h1;
  __syncthreads();

  // ---- GEMM phase ----
  const int lr = lane & 15;
  const int lq = lane >> 4;
  f32x4 acc[4] = {};

  const unsigned short* bp = W2T + (size_t)(w * 64 + lr) * H_ + lq * 8;

#pragma unroll 4
  for (int kt = 0; kt < H_ / 32; ++kt) {
    bf16x8 a = *reinterpret_cast<const bf16x8*>(&hl[lr * HP + kt * 32 + lq * 8]);
#pragma unroll
    for (int ni = 0; ni < 4; ++ni) {
      bf16x8 b = *reinterpret_cast<const bf16x8*>(bp + (size_t)ni * 16 * H_ + kt * 32);
      acc[ni] = __builtin_amdgcn_mfma_f32_16x16x32_bf16(a, b, acc[ni], 0, 0, 0);
    }
  }

#pragma unroll
  for (int ni = 0; ni < 4; ++ni) {
    const int n = w * 64 + ni * 16 + lr;
    const float bias = b2[n];
#pragma unroll
    for (int r = 0; r < 4; ++r) {
      const int m = lq * 4 + r;
      float v = acc[ni][r] + bias;
      out[(size_t)(b0 + m) * H_ + n] = v > 0.f ? v : 0.f;
    }
  }
}

// ---------------------------------------------------------------------------
extern "C" void kernel_launch(void* const* d_in, const int* in_sizes, int n_in,
                              void* d_out, int out_size, void* d_ws, size_t ws_size,
                              hipStream_t stream) {
  const int* msg   = (const int*)d_in[0];
  const float* W1  = (const float*)d_in[1];
  const float* b1  = (const float*)d_in[2];
  const float* W2  = (const float*)d_in[3];
  const float* b2  = (const float*)d_in[4];
  float* out = (float*)d_out;

  unsigned short* W2T = (unsigned short*)d_ws;                        // 512 KB
  unsigned short* W1b = (unsigned short*)((char*)d_ws + (size_t)H_ * H_ * 2);

  // prep: 5120 W1-convert blocks + 256 W2-transpose blocks
  hipLaunchKernelGGL(prep, dim3(5120 + 256), dim3(256), 0, stream,
                     W2, W1, W2T, W1b);
  hipLaunchKernelGGL(fused_gather_gemm, dim3(B_ / BT), dim3(512), 0, stream,
                     msg, W1b, b1, W2T, b2, out);
}